// Round 9
// baseline (905.978 us; speedup 1.0000x reference)
//
#include <hip/hip_runtime.h>

#define N_NODES 100000
#define N_EDGES 3200000
#define IN_DIM  29
#define HID_DIM 64
#define NBUCK   782            // ceil(N / 128)
#define BNODES  128            // dst nodes per bucket
#define CAP     5120           // slots/bucket; mean 4092, sigma ~64 -> +16 sigma
#define EPT     16
#define EPB     8192           // 512 threads * 16 edges

// ---- ws layout (4-byte units) ---------------------------------------------
#define OFF_CUR   0            // gcursor[NBUCK] (bucket sizes; region b at b*CAP)
#define OFF_DINV  1024         // dinv[N]
#define OFF_ZS    101024       // zs[2N]
#define OFF_EBUF  301024       // ebuf[NBUCK*CAP] = 4,003,840
#define OFF_XS    4304864      // xs bf16[32N] = 16N uints (8B aligned)

typedef unsigned uv2 __attribute__((ext_vector_type(2)));

static __device__ __forceinline__ unsigned short f2bf(float f) {
    unsigned u = __float_as_uint(f);
    u += 0x7fffu + ((u >> 16) & 1u);   // RNE
    return (unsigned short)(u >> 16);
}

// ---------------- partition: bucket edges by dst>>7, packed src|dl<<17 ------
__global__ __launch_bounds__(512) void partition_kernel(const int* __restrict__ ei,
        int* __restrict__ gcursor, int* __restrict__ ebuf) {
    __shared__ int lhist[NBUCK];
    __shared__ int lcur[NBUCK];
    int tid = threadIdx.x;
    for (int i = tid; i < NBUCK; i += 512) lhist[i] = 0;
    __syncthreads();

    int base = blockIdx.x * EPB + tid * EPT;     // 16-aligned; never straddles E
    int dv[EPT], sv[EPT];
    bool valid = (base < N_EDGES);
    if (valid) {
        const int4* dp = (const int4*)(ei + N_EDGES + base);
        const int4* sp = (const int4*)(ei + base);
        #pragma unroll
        for (int q = 0; q < 4; ++q) {
            int4 t = dp[q];
            dv[4*q+0] = t.x; dv[4*q+1] = t.y; dv[4*q+2] = t.z; dv[4*q+3] = t.w;
            int4 u = sp[q];
            sv[4*q+0] = u.x; sv[4*q+1] = u.y; sv[4*q+2] = u.z; sv[4*q+3] = u.w;
        }
        #pragma unroll
        for (int j = 0; j < EPT; ++j) atomicAdd(&lhist[dv[j] >> 7], 1);
    }
    __syncthreads();
    for (int i = tid; i < NBUCK; i += 512) {
        int c = lhist[i];
        lcur[i] = c ? (atomicAdd(&gcursor[i], c) + i * CAP) : 0;  // claim base
    }
    __syncthreads();
    if (valid) {
        #pragma unroll
        for (int j = 0; j < EPT; ++j) {
            int d = dv[j];
            int pos = atomicAdd(&lcur[d >> 7], 1);     // LDS cursor
            ebuf[pos] = sv[j] | ((d & 127) << 17);     // src < 2^17, dl 7 bits
        }
    }
}

// ---- degree + dinv + xs build (one block owns one bucket's 128 nodes) ------
__global__ __launch_bounds__(256) void degxs_kernel(const int* __restrict__ gcursor,
        const int* __restrict__ ebuf, const float* __restrict__ x,
        float* __restrict__ dinv, unsigned int* __restrict__ xsb) {
    __shared__ int   cnt[BNODES];
    __shared__ float dls[BNODES];
    int b = blockIdx.x, tid = threadIdx.x;
    if (tid < BNODES) cnt[tid] = 0;
    __syncthreads();
    int base = b * CAP, sz = gcursor[b];
    for (int j = tid; j < sz; j += 256)
        atomicAdd(&cnt[((unsigned)ebuf[base + j]) >> 17], 1);
    __syncthreads();
    if (tid < BNODES) {
        int node = b * BNODES + tid;
        if (node < N_NODES) {
            float dn = rsqrtf((float)cnt[tid] + 1.0f);  // +1 = self loop
            dinv[node] = dn;
            dls[tid] = dn;
        }
    }
    __syncthreads();
    for (int i = tid; i < BNODES * 16; i += 256) {      // 2 features per uint
        int dl = i >> 4, kp = i & 15;
        int nd = b * BNODES + dl;
        if (nd < N_NODES) {
            float dn = dls[dl];
            int k0 = kp * 2, k1 = k0 + 1;
            float f0 = (k0 < IN_DIM) ? x[nd * IN_DIM + k0] * dn : 0.0f;
            float f1 = (k1 < IN_DIM) ? x[nd * IN_DIM + k1] * dn : 0.0f;
            xsb[(size_t)nd * 16 + kp] = (unsigned)f2bf(f0) | ((unsigned)f2bf(f1) << 16);
        }
    }
}

// --- fused: unsorted-bucket LDS-tile scatter + W1/relu/W2 epilogue ----------
__global__ __launch_bounds__(512) void fused_kernel(const unsigned int* __restrict__ xs_,
        const int* __restrict__ gcursor, const int* __restrict__ ebuf,
        const float* __restrict__ dinv,
        const float* __restrict__ W1, const float* __restrict__ b1,
        const float* __restrict__ W2, float* __restrict__ zs) {
    __shared__ float agg[BNODES * 33];                 // 33-pad: spread banks
    __shared__ float w1s[IN_DIM * HID_DIM];
    __shared__ float b1s[HID_DIM];
    __shared__ float w2s[HID_DIM * 2];
    int tid = threadIdx.x, b = blockIdx.x;
    for (int i = tid; i < IN_DIM * HID_DIM; i += 512) w1s[i] = W1[i];
    if (tid < HID_DIM) {
        b1s[tid] = b1[tid];
        w2s[tid * 2 + 0] = W2[tid * 2 + 0];
        w2s[tid * 2 + 1] = W2[tid * 2 + 1];
    }
    // seed tile with self-loop rows (writes all 32 used cols; col 32 unused)
    for (int i = tid; i < BNODES * 16; i += 512) {
        int dl = i >> 4, kp = i & 15;
        int nd = b * BNODES + dl;
        unsigned u = (nd < N_NODES) ? xs_[(size_t)nd * 16 + kp] : 0u;
        agg[dl * 33 + kp * 2 + 0] = __uint_as_float(u << 16);
        agg[dl * 33 + kp * 2 + 1] = __uint_as_float(u & 0xFFFF0000u);
    }
    __syncthreads();

    const uv2* xsbv = (const uv2*)xs_;                 // row = 8 uv2 (64 B)
    int g = tid >> 3, m = tid & 7;                     // 64 groups x 8 lanes
    int base = b * CAP, sz = gcursor[b];
    int last = sz - 1;
    for (int e = g; e < sz; e += 256) {                // 4 edges in flight/thread
        int e1 = e + 64, e2 = e + 128, e3 = e + 192;
        unsigned p0 = (unsigned)ebuf[base + e];
        unsigned p1 = (unsigned)ebuf[base + min(e1, last)];
        unsigned p2 = (unsigned)ebuf[base + min(e2, last)];
        unsigned p3 = (unsigned)ebuf[base + min(e3, last)];
        uv2 a0 = xsbv[(size_t)(p0 & 0x1FFFF) * 8 + m];
        uv2 a1 = xsbv[(size_t)(p1 & 0x1FFFF) * 8 + m];
        uv2 a2 = xsbv[(size_t)(p2 & 0x1FFFF) * 8 + m];
        uv2 a3 = xsbv[(size_t)(p3 & 0x1FFFF) * 8 + m];
        {
            int o = (int)(p0 >> 17) * 33 + m * 4;
            atomicAdd(&agg[o + 0], __uint_as_float(a0.x << 16));
            atomicAdd(&agg[o + 1], __uint_as_float(a0.x & 0xFFFF0000u));
            atomicAdd(&agg[o + 2], __uint_as_float(a0.y << 16));
            atomicAdd(&agg[o + 3], __uint_as_float(a0.y & 0xFFFF0000u));
        }
        if (e1 < sz) {
            int o = (int)(p1 >> 17) * 33 + m * 4;
            atomicAdd(&agg[o + 0], __uint_as_float(a1.x << 16));
            atomicAdd(&agg[o + 1], __uint_as_float(a1.x & 0xFFFF0000u));
            atomicAdd(&agg[o + 2], __uint_as_float(a1.y << 16));
            atomicAdd(&agg[o + 3], __uint_as_float(a1.y & 0xFFFF0000u));
        }
        if (e2 < sz) {
            int o = (int)(p2 >> 17) * 33 + m * 4;
            atomicAdd(&agg[o + 0], __uint_as_float(a2.x << 16));
            atomicAdd(&agg[o + 1], __uint_as_float(a2.x & 0xFFFF0000u));
            atomicAdd(&agg[o + 2], __uint_as_float(a2.y << 16));
            atomicAdd(&agg[o + 3], __uint_as_float(a2.y & 0xFFFF0000u));
        }
        if (e3 < sz) {
            int o = (int)(p3 >> 17) * 33 + m * 4;
            atomicAdd(&agg[o + 0], __uint_as_float(a3.x << 16));
            atomicAdd(&agg[o + 1], __uint_as_float(a3.x & 0xFFFF0000u));
            atomicAdd(&agg[o + 2], __uint_as_float(a3.y << 16));
            atomicAdd(&agg[o + 3], __uint_as_float(a3.y & 0xFFFF0000u));
        }
    }
    __syncthreads();

    int wave = tid >> 6, lane = tid & 63;              // 8 waves, 16 nodes each
    for (int dl = wave; dl < BNODES; dl += 8) {
        int node = b * BNODES + dl;
        if (node >= N_NODES) break;
        float dn = dinv[node];
        float a = (lane < 32) ? agg[dl * 33 + lane] * dn : 0.0f;
        float h = b1s[lane];
        #pragma unroll
        for (int kk = 0; kk < IN_DIM; ++kk)
            h = fmaf(__shfl(a, kk), w1s[kk * HID_DIM + lane], h);
        h = fmaxf(h, 0.0f);
        float z0 = h * w2s[lane * 2 + 0];
        float z1 = h * w2s[lane * 2 + 1];
        #pragma unroll
        for (int off = 32; off > 0; off >>= 1) {
            z0 += __shfl_down(z0, off);
            z1 += __shfl_down(z1, off);
        }
        if (lane == 0) {                               // pre-scale by src dinv
            zs[node * 2 + 0] = z0 * dn;
            zs[node * 2 + 1] = z1 * dn;
        }
    }
}

// --- agg2: unsorted-bucket LDS scatter of zs + finalize ---------------------
__global__ __launch_bounds__(256) void agg2_kernel(const float* __restrict__ zs,
        const int* __restrict__ gcursor, const int* __restrict__ ebuf,
        const float* __restrict__ dinv, const float* __restrict__ b2,
        float* __restrict__ out) {
    __shared__ float aggz[BNODES * 2];
    int tid = threadIdx.x, b = blockIdx.x;
    {   // seed with self term zs[node]
        int nd = b * BNODES + (tid >> 1);
        aggz[tid] = (nd < N_NODES) ? zs[nd * 2 + (tid & 1)] : 0.0f;
    }
    __syncthreads();
    const float2* zs2 = (const float2*)zs;
    int base = b * CAP, sz = gcursor[b];
    int last = sz - 1;
    for (int e = tid; e < sz; e += 1024) {             // 4 edges in flight
        int e1 = e + 256, e2 = e + 512, e3 = e + 768;
        unsigned p0 = (unsigned)ebuf[base + e];
        unsigned p1 = (unsigned)ebuf[base + min(e1, last)];
        unsigned p2 = (unsigned)ebuf[base + min(e2, last)];
        unsigned p3 = (unsigned)ebuf[base + min(e3, last)];
        float2 z0 = zs2[p0 & 0x1FFFF];
        float2 z1 = zs2[p1 & 0x1FFFF];
        float2 z2 = zs2[p2 & 0x1FFFF];
        float2 z3 = zs2[p3 & 0x1FFFF];
        { int o = (int)(p0 >> 17) * 2;
          atomicAdd(&aggz[o], z0.x); atomicAdd(&aggz[o + 1], z0.y); }
        if (e1 < sz) { int o = (int)(p1 >> 17) * 2;
          atomicAdd(&aggz[o], z1.x); atomicAdd(&aggz[o + 1], z1.y); }
        if (e2 < sz) { int o = (int)(p2 >> 17) * 2;
          atomicAdd(&aggz[o], z2.x); atomicAdd(&aggz[o + 1], z2.y); }
        if (e3 < sz) { int o = (int)(p3 >> 17) * 2;
          atomicAdd(&aggz[o], z3.x); atomicAdd(&aggz[o + 1], z3.y); }
    }
    __syncthreads();
    {
        int nd = b * BNODES + (tid >> 1);
        if (nd < N_NODES) {
            int c = tid & 1;
            out[nd * 2 + c] = dinv[nd] * aggz[tid] + b2[c];
        }
    }
}

extern "C" void kernel_launch(void* const* d_in, const int* in_sizes, int n_in,
                              void* d_out, int out_size, void* d_ws, size_t ws_size,
                              hipStream_t stream) {
    const float* x  = (const float*)d_in[0];
    const int*   ei = (const int*)d_in[1];
    const float* W1 = (const float*)d_in[2];
    const float* b1 = (const float*)d_in[3];
    const float* W2 = (const float*)d_in[4];
    const float* b2 = (const float*)d_in[5];
    float* out = (float*)d_out;

    int*   wsi     = (int*)d_ws;
    float* wsf     = (float*)d_ws;
    int*   gcursor = wsi + OFF_CUR;
    float* dinv    = wsf + OFF_DINV;
    float* zs      = wsf + OFF_ZS;
    int*   ebuf    = wsi + OFF_EBUF;
    unsigned int* xsb = (unsigned int*)(wsi + OFF_XS);

    hipMemsetAsync(gcursor, 0, NBUCK * sizeof(int), stream);
    partition_kernel<<<(N_EDGES + EPB - 1) / EPB, 512, 0, stream>>>(ei, gcursor, ebuf);
    degxs_kernel<<<NBUCK, 256, 0, stream>>>(gcursor, ebuf, x, dinv, xsb);
    fused_kernel<<<NBUCK, 512, 0, stream>>>(xsb, gcursor, ebuf, dinv, W1, b1, W2, zs);
    agg2_kernel<<<NBUCK, 256, 0, stream>>>(zs, gcursor, ebuf, dinv, b2, out);
}

// Round 10
// 237.880 us; speedup vs baseline: 3.8085x; 3.8085x over previous
//
#include <hip/hip_runtime.h>

#define N_NODES 100000
#define N_EDGES 3200000
#define IN_DIM  29
#define HID_DIM 64
#define NBUCK   1563           // ceil(N / 64)
#define BNODES  64             // dst nodes per bucket
#define CAP     2560           // slots/bucket; mean 2047, sigma ~45 -> +11 sigma
#define EPT     32
#define EPB     16384          // 512 threads * 32 edges

// ---- ws layout (4-byte units) ---------------------------------------------
#define OFF_CUR   0            // gcursor[NBUCK] (bucket sizes; region b at b*CAP)
#define OFF_DEGC  2048         // degc[N]
#define OFF_DINV  102080       // dinv[N]
#define OFF_ROWS  202112       // rowStart[N]
#define OFF_ROWE  302144       // rowEnd[N]
#define OFF_ZS    402176       // zs[2N]
#define OFF_EBUF  602240       // ebuf[NBUCK*CAP] = 4,001,280
#define OFF_XS    4603520      // xs bf16[32N] = 16N uints
// total 6,204,032 words = 24.8 MB

typedef unsigned uv2 __attribute__((ext_vector_type(2)));

static __device__ __forceinline__ unsigned short f2bf(float f) {
    unsigned u = __float_as_uint(f);
    u += 0x7fffu + ((u >> 16) & 1u);   // RNE
    return (unsigned short)(u >> 16);
}

static __device__ __forceinline__ void unpack_add(float4& acc, uv2 a) {
    acc.x += __uint_as_float(a.x << 16);
    acc.y += __uint_as_float(a.x & 0xFFFF0000u);
    acc.z += __uint_as_float(a.y << 16);
    acc.w += __uint_as_float(a.y & 0xFFFF0000u);
}

// ---------------- partition: bucket edges by dst>>6, packed src|dl<<17 ------
__global__ __launch_bounds__(512) void partition_kernel(const int* __restrict__ ei,
        int* __restrict__ gcursor, int* __restrict__ ebuf) {
    __shared__ int lhist[NBUCK];
    __shared__ int lcur[NBUCK];
    int tid = threadIdx.x;
    for (int i = tid; i < NBUCK; i += 512) lhist[i] = 0;
    __syncthreads();

    int base = blockIdx.x * EPB + tid * EPT;     // 32-aligned; never straddles E
    int dv[EPT], sv[EPT];
    bool valid = (base < N_EDGES);
    if (valid) {
        const int4* dp = (const int4*)(ei + N_EDGES + base);
        const int4* sp = (const int4*)(ei + base);
        #pragma unroll
        for (int q = 0; q < 8; ++q) {
            int4 t = dp[q];
            dv[4*q+0] = t.x; dv[4*q+1] = t.y; dv[4*q+2] = t.z; dv[4*q+3] = t.w;
            int4 u = sp[q];
            sv[4*q+0] = u.x; sv[4*q+1] = u.y; sv[4*q+2] = u.z; sv[4*q+3] = u.w;
        }
        #pragma unroll
        for (int j = 0; j < EPT; ++j) atomicAdd(&lhist[dv[j] >> 6], 1);
    }
    __syncthreads();
    for (int i = tid; i < NBUCK; i += 512) {
        int c = lhist[i];
        lcur[i] = c ? (atomicAdd(&gcursor[i], c) + i * CAP) : 0;  // claim base
    }
    __syncthreads();
    if (valid) {
        #pragma unroll
        for (int j = 0; j < EPT; ++j) {
            int d = dv[j];
            int pos = atomicAdd(&lcur[d >> 6], 1);     // LDS cursor
            ebuf[pos] = sv[j] | ((d & 63) << 17);      // src 17 bits, dl 6 bits
        }
    }
}

// ---- per-bucket degree count -> degc/dinv, and xs = bf16(x*dinv) -----------
__global__ __launch_bounds__(256) void degcnt_kernel(const int* __restrict__ gcursor,
        const int* __restrict__ ebuf, const float* __restrict__ x,
        int* __restrict__ degc, float* __restrict__ dinv,
        unsigned int* __restrict__ xsb) {
    __shared__ int   cnt[BNODES];
    __shared__ float dls[BNODES];
    int b = blockIdx.x, tid = threadIdx.x;
    if (tid < BNODES) cnt[tid] = 0;
    __syncthreads();
    int base = b * CAP, sz = gcursor[b];
    for (int j = tid; j < sz; j += 256)
        atomicAdd(&cnt[((unsigned)ebuf[base + j]) >> 17], 1);
    __syncthreads();
    if (tid < BNODES) {
        int node = b * BNODES + tid;
        if (node < N_NODES) {
            int c = cnt[tid];
            degc[node] = c;
            float dn = rsqrtf((float)c + 1.0f);        // +1 = self loop
            dinv[node] = dn;
            dls[tid] = dn;
        }
    }
    __syncthreads();
    for (int i = tid; i < BNODES * 16; i += 256) {     // 2 features per uint
        int dl = i >> 4, kp = i & 15;
        int nd = b * BNODES + dl;
        if (nd < N_NODES) {
            float dn = dls[dl];
            int k0 = kp * 2, k1 = k0 + 1;
            float f0 = (k0 < IN_DIM) ? x[nd * IN_DIM + k0] * dn : 0.0f;
            float f1 = (k1 < IN_DIM) ? x[nd * IN_DIM + k1] * dn : 0.0f;
            xsb[(size_t)nd * 16 + kp] = (unsigned)f2bf(f0) | ((unsigned)f2bf(f1) << 16);
        }
    }
}

// --- sortfused: LDS counting-sort of own bucket + gather + W1/relu/W2 -------
__global__ __launch_bounds__(256) void sortfused_kernel(const unsigned int* __restrict__ xs_,
        const int* __restrict__ gcursor, int* __restrict__ ebuf,
        const int* __restrict__ degc,
        int* __restrict__ rowStart, int* __restrict__ rowEnd,
        const float* __restrict__ W1, const float* __restrict__ b1,
        const float* __restrict__ W2, float* __restrict__ zs) {
    __shared__ float w1s[IN_DIM * HID_DIM];            // 7.4 KB
    __shared__ float b1s[HID_DIM];
    __shared__ float w2s[HID_DIM * 2];
    __shared__ int   cnt[BNODES];
    __shared__ int   rs_l[BNODES];
    __shared__ int   cur[BNODES];
    __shared__ int   stage[CAP];                       // 10 KB
    int tid = threadIdx.x, b = blockIdx.x;
    for (int i = tid; i < IN_DIM * HID_DIM; i += 256) w1s[i] = W1[i];
    if (tid < HID_DIM) {
        b1s[tid] = b1[tid];
        w2s[tid * 2 + 0] = W2[tid * 2 + 0];
        w2s[tid * 2 + 1] = W2[tid * 2 + 1];
    }
    int base = b * CAP, sz = gcursor[b];
    if (tid < BNODES) {
        int node = b * BNODES + tid;
        cnt[tid] = (node < N_NODES) ? degc[node] : 0;
    }
    __syncthreads();

    if (tid < 64) {                                    // wave-0 shuffle scan
        int c = cnt[tid];
        int incl = c;
        #pragma unroll
        for (int off = 1; off < 64; off <<= 1) {
            int t = __shfl_up(incl, off);
            if (tid >= off) incl += t;
        }
        int excl = incl - c;
        rs_l[tid] = excl;
        cur[tid]  = excl;
        int node = b * BNODES + tid;
        if (node < N_NODES) {
            rowStart[node] = base + excl;              // for agg2
            rowEnd[node]   = base + excl + c;
        }
    }
    __syncthreads();

    for (int j = tid; j < sz; j += 256) {              // place into LDS stage
        unsigned p = (unsigned)ebuf[base + j];
        int pos = atomicAdd(&cur[p >> 17], 1);
        stage[pos] = p & 0x1FFFF;
    }
    __syncthreads();
    for (int j = tid; j < sz; j += 256)                // sorted writeback (agg2)
        ebuf[base + j] = stage[j];

    // gather + MLP: 4 waves x 16 nodes; 8 streams x 8 lanes; masked unroll-4
    int wave = tid >> 6, lane = tid & 63;
    int q = lane >> 3, m = lane & 7;
    const uv2* xsbv = (const uv2*)xs_;                 // row = 8 uv2 (64 B)
    for (int dl = wave; dl < BNODES; dl += 4) {
        int node = b * BNODES + dl;
        if (node >= N_NODES) break;
        float4 acc = make_float4(0.f, 0.f, 0.f, 0.f);
        if (q == 0)                                    // self loop in stream 0
            unpack_add(acc, xsbv[(size_t)node * 8 + m]);
        int rs = rs_l[dl], re = rs + cnt[dl];
        int last = re - 1;
        for (int j = rs + q; j < re; j += 32) {        // 4 gathers in flight
            int j1 = j + 8, j2 = j + 16, j3 = j + 24;
            int s0 = stage[j];
            int s1 = stage[min(j1, last)];
            int s2 = stage[min(j2, last)];
            int s3 = stage[min(j3, last)];
            uv2 a0 = xsbv[(size_t)s0 * 8 + m];
            uv2 a1 = xsbv[(size_t)s1 * 8 + m];
            uv2 a2 = xsbv[(size_t)s2 * 8 + m];
            uv2 a3 = xsbv[(size_t)s3 * 8 + m];
            unpack_add(acc, a0);
            if (j1 < re) unpack_add(acc, a1);
            if (j2 < re) unpack_add(acc, a2);
            if (j3 < re) unpack_add(acc, a3);
        }
        #pragma unroll
        for (int msk = 8; msk <= 32; msk <<= 1) {      // fold 8 streams
            acc.x += __shfl_xor(acc.x, msk);
            acc.y += __shfl_xor(acc.y, msk);
            acc.z += __shfl_xor(acc.z, msk);
            acc.w += __shfl_xor(acc.w, msk);
        }
        float dn = rsqrtf((float)cnt[dl] + 1.0f);
        acc.x *= dn; acc.y *= dn; acc.z *= dn; acc.w *= dn;

        float h = b1s[lane];
        #pragma unroll
        for (int kk = 0; kk < IN_DIM; ++kk) {          // comp pick compile-time
            float comp = ((kk & 3) == 0) ? acc.x : ((kk & 3) == 1) ? acc.y
                       : ((kk & 3) == 2) ? acc.z : acc.w;
            h = fmaf(__shfl(comp, kk >> 2), w1s[kk * HID_DIM + lane], h);
        }
        h = fmaxf(h, 0.0f);

        float z0 = h * w2s[lane * 2 + 0];
        float z1 = h * w2s[lane * 2 + 1];
        #pragma unroll
        for (int off = 32; off > 0; off >>= 1) {
            z0 += __shfl_down(z0, off);
            z1 += __shfl_down(z1, off);
        }
        if (lane == 0) {                               // pre-scale by src dinv
            zs[node * 2 + 0] = z0 * dn;
            zs[node * 2 + 1] = z1 * dn;
        }
    }
}

// ------- agg2: 16-lane group per node, masked unroll-2 + finalize -----------
__global__ __launch_bounds__(256) void agg2_kernel(const float* __restrict__ zs,
        const int* __restrict__ rowStart, const int* __restrict__ rowEnd,
        const int* __restrict__ ebuf, const float* __restrict__ dinv,
        const float* __restrict__ b2, float* __restrict__ out) {
    int tid = threadIdx.x;
    int node = blockIdx.x * 16 + (tid >> 4);
    if (node >= N_NODES) return;
    int gl = tid & 15;
    const float2* zs2 = (const float2*)zs;
    float a0 = 0.0f, a1 = 0.0f, c0 = 0.0f, c1 = 0.0f;
    int rs = rowStart[node], re = rowEnd[node];
    int last = re - 1;
    for (int j = rs + gl; j < re; j += 32) {           // masked: 2 in flight
        int j1 = j + 16;
        float2 za = zs2[ebuf[j]];
        float2 zb = zs2[ebuf[min(j1, last)]];
        a0 += za.x; a1 += za.y;
        if (j1 < re) { c0 += zb.x; c1 += zb.y; }
    }
    a0 += c0; a1 += c1;
    a0 += __shfl_xor(a0, 8); a1 += __shfl_xor(a1, 8);
    a0 += __shfl_xor(a0, 4); a1 += __shfl_xor(a1, 4);
    a0 += __shfl_xor(a0, 2); a1 += __shfl_xor(a1, 2);
    a0 += __shfl_xor(a0, 1); a1 += __shfl_xor(a1, 1);
    if (gl == 0) {
        float dn = dinv[node];
        float2 zself = zs2[node];
        float2 o;
        o.x = dn * (a0 + zself.x) + b2[0];
        o.y = dn * (a1 + zself.y) + b2[1];
        ((float2*)out)[node] = o;
    }
}

extern "C" void kernel_launch(void* const* d_in, const int* in_sizes, int n_in,
                              void* d_out, int out_size, void* d_ws, size_t ws_size,
                              hipStream_t stream) {
    const float* x  = (const float*)d_in[0];
    const int*   ei = (const int*)d_in[1];
    const float* W1 = (const float*)d_in[2];
    const float* b1 = (const float*)d_in[3];
    const float* W2 = (const float*)d_in[4];
    const float* b2 = (const float*)d_in[5];
    float* out = (float*)d_out;

    int*   wsi      = (int*)d_ws;
    float* wsf      = (float*)d_ws;
    int*   gcursor  = wsi + OFF_CUR;
    int*   degc     = wsi + OFF_DEGC;
    float* dinv     = wsf + OFF_DINV;
    int*   rowStart = wsi + OFF_ROWS;
    int*   rowEnd   = wsi + OFF_ROWE;
    float* zs       = wsf + OFF_ZS;
    int*   ebuf     = wsi + OFF_EBUF;
    unsigned int* xsb = (unsigned int*)(wsi + OFF_XS);

    hipMemsetAsync(gcursor, 0, NBUCK * sizeof(int), stream);
    partition_kernel<<<(N_EDGES + EPB - 1) / EPB, 512, 0, stream>>>(ei, gcursor, ebuf);
    degcnt_kernel<<<NBUCK, 256, 0, stream>>>(gcursor, ebuf, x, degc, dinv, xsb);
    sortfused_kernel<<<NBUCK, 256, 0, stream>>>(xsb, gcursor, ebuf, degc,
                                                rowStart, rowEnd, W1, b1, W2, zs);
    agg2_kernel<<<(N_NODES + 15) / 16, 256, 0, stream>>>(zs, rowStart, rowEnd, ebuf, dinv, b2, out);
}